// Round 5
// baseline (318.348 us; speedup 1.0000x reference)
//
#include <hip/hip_runtime.h>
#include <cmath>

// PhaseAwareClassifier on MI355X — R22: column-owner waves, barrier-free
// time loop.
// R21 post-mortem: VALUBusy+MfmaUtil ~99% (issue-saturated); step = LDS-unit
// 8.2k cyc (680 b128 reads: A x4 redundant, B x4 redundant) + 2-barrier
// lockstep + mg3 straggler. Occupancy/setprio/hoists all ~0.
// KEY FACT: the recurrence is column-independent (einsum mixes switch rows
// only, never (L,m)). R22: each wave OWNS 32 cols end-to-end:
//  - private per-wave OB (18ch x 32 x 8 x 2B x 2 = 18.4 KB/wave): B-reads
//    redundancy 1 -> 440 reads/step/CU (vs 680); writes wave-private.
//  - ZERO barriers in the t-loop (same-wave LDS program order suffices);
//    epilogue of one wave overlaps GEMM of another; no mg imbalance.
//  - 256 thr/block, 4 waves, 1/SIMD; __launch_bounds__(256,1) -> VGPR cap
//    512 (acc 144 + ~70 working ~ 220). R19 lesson inverted: raise cap.
// Bit-exact: per-acc MFMA chain order (kt ascending, CPAIR order), epilogue
// float sequence, inj fmaf identical to R20/R21. t=1 kt<2 and t=9 tail kept.
// LDS: conn 82,944 + OBP 73,728 + gsp 576 = 157,248 B.

#define NSTEPS  10
#define INJ_ST  4
#define MT      144          // padded M (9 tiles of 16)

typedef __bf16 bf16x8 __attribute__((ext_vector_type(8)));
typedef __bf16 bf16x4 __attribute__((ext_vector_type(4)));
typedef short  short8 __attribute__((ext_vector_type(8)));
typedef float  f32x4  __attribute__((ext_vector_type(4)));

// workspace layout (float offsets)
#define WS_MAX    0          // 1      enc_max (uint-ordered float)
#define WS_ENERGY 64         // 1280   energy[b][10]
#define WS_GSP    2048       // 144    g2q[j] = -0.5*log2(e)*softplus(gain)
#define WS_CONN   4096       // 2 bf16 mats [20][144][8] chunked: Cr, Ci

// fused prep: blocks 0..97 = image absmax; blocks 98.. = conn + gsp tables
__global__ void k_pre(const float* __restrict__ img,
                      const float* __restrict__ cr, const float* __restrict__ ci,
                      const float* __restrict__ phase, const float* __restrict__ gain,
                      float* ws) {
    if (blockIdx.x < 98) {
        __shared__ float sm[256];
        float v = 0.f;
        for (int i = blockIdx.x * 256 + threadIdx.x; i < 128 * 28 * 28; i += 98 * 256)
            v = fmaxf(v, fabsf(img[i]));
        sm[threadIdx.x] = v;
        __syncthreads();
        for (int s = 128; s > 0; s >>= 1) {
            if (threadIdx.x < s) sm[threadIdx.x] = fmaxf(sm[threadIdx.x], sm[threadIdx.x + s]);
            __syncthreads();
        }
        if (threadIdx.x == 0)
            atomicMax((unsigned int*)(ws + WS_MAX), __float_as_uint(sm[0]));
        return;
    }
    int i = (blockIdx.x - 98) * 256 + threadIdx.x;
    __bf16* Cb = (__bf16*)(ws + WS_CONN);
    const int NCE = MT * 160;              // 23040 (m,k) pairs
    if (i < NCE) {
        int m = i / 160, k = i % 160;
        float vr = 0.f, vi = 0.f;
        if (m < 131 && k < 131) {
            float a = cr[k * 131 + m], b = ci[k * 131 + m];
            float ph = phase[m];
            float cp = cosf(ph), sp = sinf(ph);
            vr = a * cp - b * sp;
            vi = a * sp + b * cp;
        }
        int ca = ((k >> 3) * MT + m) * 8 + (k & 7);    // chunked addr
        Cb[ca]       = (__bf16)vr;
        Cb[NCE + ca] = (__bf16)vi;
    } else if (i < NCE + MT) {
        int j = i - NCE;
        float g = 0.f;
        if (j < 131) {
            float x = gain[j];
            g = (x > 20.f) ? x : log1pf(expf(x));  // softplus
        }
        ws[WS_GSP + j] = g * -0.72134754543f;       // -2*log2(e)*g / 4
    }
}

static __device__ __forceinline__ f32x4 MF(bf16x8 a, bf16x8 b, f32x4 c) {
    return __builtin_amdgcn_mfma_f32_16x16x32_bf16(a, b, c, 0, 0, 0);
}
static __device__ __forceinline__ bf16x8 bneg(bf16x8 a) {
    short8 t = __builtin_bit_cast(short8, a) ^ (short8)(short)0x8000;
    return __builtin_bit_cast(bf16x8, t);
}

// one complex 16x16 tile accumulation; order identical to R17..R21.
#define CPAIR(AR, AI, BR, BI, BNI, P)                                  \
    accr[P] = MF(AR, BR,  accr[P]);                                    \
    accr[P] = MF(AI, BNI, accr[P]);                                    \
    acci[P] = MF(AR, BI,  acci[P]);                                    \
    acci[P] = MF(AI, BR,  acci[P]);

__global__ __launch_bounds__(256, 1)
void k_main(const float* __restrict__ img, const float* __restrict__ ws,
            float* __restrict__ energy) {
    __shared__ __bf16 CrL[18 * MT * 8];            // 41,472 B
    __shared__ __bf16 CiL[18 * MT * 8];            // 41,472 B
    __shared__ __bf16 OBP[2][4][18 * 32 * 8];      // 73,728 B  [r/i][wave][...]
    __shared__ float  gspL[144];                   // 576 B
    // total 157,248 B -> 1 block/CU, 4 waves = 1/SIMD, col-owner layout.

    const int tid  = threadIdx.x;
    const int lane = tid & 63;
    const int ln15 = lane & 15;
    const int quad = lane >> 4;
    const int w    = __builtin_amdgcn_readfirstlane(tid >> 6);  // 0..3
    const int b    = blockIdx.x >> 3;               // 8 blocks per image

    __bf16* __restrict__ OWr = &OBP[0][w][0];
    __bf16* __restrict__ OWi = &OBP[1][w][0];
    float* scrE = (float*)CrL;                      // alias: end only

    // injection scaling (identical rounding chain to R20/R21)
    const float mx = ws[WS_MAX];
    const float sc = (mx > 1e-8f) ? (1.02f / mx) : 1.02f;   // 0.85*4*0.3
    const int   imgb = b * 784 + (ln15 >> 2) * 28 + (ln15 & 3);

    // wave w owns block cols [32w, 32w+32): l = (blk&7)*8 + 2w + nt, m = ln15
    float wls[2];
#pragma unroll
    for (int nt = 0; nt < 2; ++nt) {
        int l = ((blockIdx.x & 7) * 8 + 2 * w + nt) & 63;
        wls[nt] = 1.0f - fabsf((float)l - 32.0f) * (1.0f / 64.0f);
    }

    // stage conn chunks 0..17 + gsp -> LDS (only barrier before the end)
    {
        const int4* srcR = (const int4*)(ws + WS_CONN);
        const int4* srcI = (const int4*)(ws + WS_CONN + (MT * 160 / 2));
        int4* dstR = (int4*)CrL;
        int4* dstI = (int4*)CiL;
        for (int i = tid; i < 2592; i += 256) { dstR[i] = srcR[i]; dstI[i] = srcI[i]; }
        if (tid < 144) gspL[tid] = ws[WS_GSP + tid];
    }

    f32x4 accr[18], acci[18];                       // p = mt*2 + nt
#pragma unroll
    for (int p = 0; p < 18; ++p) { accr[p] = (f32x4)0.f; acci[p] = (f32x4)0.f; }

    // injection: rows j<49 (tiles 0..3); one img load feeds both nt accs
    auto inj_add = [&]() {
#pragma unroll
        for (int mt = 0; mt < 4; ++mt) {
#pragma unroll
            for (int r = 0; r < 4; ++r) {
                int j = mt * 16 + quad * 4 + r;
                if (j < 49) {           // mt<3 always true for j<48 rows etc.
                    int pi = j / 7, pj = j % 7;
                    float px = img[imgb + pi * 112 + pj * 4];
                    float t  = px * sc;
                    accr[mt * 2 + 0][r] = fmaf(t, wls[0], accr[mt * 2 + 0][r]);
                    accr[mt * 2 + 1][r] = fmaf(t, wls[1], accr[mt * 2 + 1][r]);
                }
            }
        }
    };

    // epilogue: out = a * tanh(g*|f|)/|f| (0.25 folded in g2q), write own OB
    auto epilogue = [&]() {
#pragma unroll
        for (int mt = 0; mt < 9; ++mt) {
            f32x4 g2v = *(const f32x4*)(gspL + mt * 16 + quad * 4);
#pragma unroll
            for (int nt = 0; nt < 2; ++nt) {
                const int p = mt * 2 + nt;
                bf16x4 pr, pi;
#pragma unroll
                for (int r = 0; r < 4; ++r) {
                    float ar = accr[p][r], ai = acci[p][r];
                    float mag2 = fmaf(ar, ar, fmaf(ai, ai, 1.6e-7f));
                    float rsq  = __builtin_amdgcn_rsqf(mag2);
                    float e    = __builtin_amdgcn_exp2f(g2v[r] * (mag2 * rsq));
                    float u    = __builtin_amdgcn_rcpf(1.0f + e);
                    float th   = fmaf(-2.0f, e * u, 1.0f);
                    float scv  = th * rsq;
                    pr[r] = (__bf16)(ar * scv); pi[r] = (__bf16)(ai * scv);
                }
                const int off = ((mt * 2 + (quad >> 1)) * 32 + nt * 16 + ln15) * 8
                              + (quad & 1) * 4;
                *(bf16x4*)(OWr + off) = pr;
                *(bf16x4*)(OWi + off) = pi;
            }
        }
    };

    __syncthreads();                                // conn + gsp staged

    inj_add();                                      // t = 0 (out is zero)
    epilogue();                                     // no barrier: wave-private

    // ---- time loop: ZERO barriers (each wave owns its columns) ----
#pragma unroll 1
    for (int t = 1; t < NSTEPS - 1; ++t) {
#pragma unroll
        for (int p = 0; p < 18; ++p) { accr[p] *= 0.85f; acci[p] *= 0.85f; }
        if (t < INJ_ST) inj_add();

        // t=1: out(0) rows >=49 exactly zero -> kt 0,1 only.
        const int ktEnd = (t == 1) ? 2 : 5;
        // kch 18,19 remap to chunk 17 (zeros both sides). unroll(1): R15.
#pragma unroll 1
        for (int kt = 0; kt < ktEnd; ++kt) {
            const int kch = kt * 4 + quad;
            const int rk  = (kch > 17) ? 17 : kch;
            const int bb  = (rk * 32 + ln15) * 8;
            bf16x8 br0 = *(const bf16x8*)(OWr + bb);
            bf16x8 bi0 = *(const bf16x8*)(OWi + bb);
            bf16x8 br1 = *(const bf16x8*)(OWr + bb + 128);
            bf16x8 bi1 = *(const bf16x8*)(OWi + bb + 128);
            bf16x8 bn0 = bneg(bi0);
            bf16x8 bn1 = bneg(bi1);
            const int ab = (rk * MT + ln15) * 8;
#pragma unroll
            for (int mt = 0; mt < 9; ++mt) {
                bf16x8 ar = *(const bf16x8*)(CrL + ab + mt * 128);
                bf16x8 ai = *(const bf16x8*)(CiL + ab + mt * 128);
                CPAIR(ar, ai, br0, bi0, bn0, mt * 2)
                CPAIR(ar, ai, br1, bi1, bn1, mt * 2 + 1)
            }
        }
        epilogue();                                 // wave-private, no barrier
    }

    // ---- t = 9: only rows 121..130 (tiles 7,8) feed energy; all waves ----
    {
#pragma unroll
        for (int p = 14; p < 18; ++p) { accr[p] *= 0.85f; acci[p] *= 0.85f; }
#pragma unroll 1
        for (int kt = 0; kt < 5; ++kt) {
            const int kch = kt * 4 + quad;
            const int rk  = (kch > 17) ? 17 : kch;
            const int bb  = (rk * 32 + ln15) * 8;
            bf16x8 br0 = *(const bf16x8*)(OWr + bb);
            bf16x8 bi0 = *(const bf16x8*)(OWi + bb);
            bf16x8 br1 = *(const bf16x8*)(OWr + bb + 128);
            bf16x8 bi1 = *(const bf16x8*)(OWi + bb + 128);
            bf16x8 bn0 = bneg(bi0);
            bf16x8 bn1 = bneg(bi1);
            const int ab = (rk * MT + ln15) * 8;
            bf16x8 ar7 = *(const bf16x8*)(CrL + ab + 7 * 128);
            bf16x8 ai7 = *(const bf16x8*)(CiL + ab + 7 * 128);
            bf16x8 ar8 = *(const bf16x8*)(CrL + ab + 8 * 128);
            bf16x8 ai8 = *(const bf16x8*)(CiL + ab + 8 * 128);
            CPAIR(ar7, ai7, br0, bi0, bn0, 14)
            CPAIR(ar7, ai7, br1, bi1, bn1, 15)
            CPAIR(ar8, ai8, br0, bi0, bn0, 16)
            CPAIR(ar8, ai8, br1, bi1, bn1, 17)
        }
    }
    __syncthreads();       // all CrL A-reads done before scrE (alias) writes

    // energy rows: fp32 |out|^2 -> scrE (aliases CrL)
#pragma unroll
    for (int mt = 7; mt < 9; ++mt) {
#pragma unroll
        for (int nt = 0; nt < 2; ++nt) {
            const int p = mt * 2 + nt;
            const int n = w * 32 + nt * 16 + ln15;
#pragma unroll
            for (int r = 0; r < 4; ++r) {
                int j = mt * 16 + quad * 4 + r;
                if (j >= 121 && j <= 130) {
                    float ar = accr[p][r], ai = acci[p][r];
                    float mag2 = fmaf(ar, ar, fmaf(ai, ai, 1.6e-7f));
                    float rsq  = __builtin_amdgcn_rsqf(mag2);
                    float e    = __builtin_amdgcn_exp2f(gspL[j] * (mag2 * rsq));
                    float u    = __builtin_amdgcn_rcpf(1.0f + e);
                    float th   = fmaf(-2.0f, e * u, 1.0f);
                    float scv  = th * rsq;
                    float orv = ar * scv, oiv = ai * scv;
                    scrE[(j - 121) * 128 + n] = orv * orv + oiv * oiv;
                }
            }
        }
    }
    __syncthreads();       // scrE complete

    // ---- energy: scrE[10][128] holds exact fp32 |out|^2 ----
    if (tid < 10) {
        float ssum = 0.f;
        for (int cc = 0; cc < 128; ++cc) ssum += scrE[tid * 128 + cc];
        atomicAdd(energy + b * 10 + tid, ssum);
    }
}

__global__ void k_readout(const float* __restrict__ ws,
                          const float* __restrict__ W,
                          const float* __restrict__ bias,
                          float* __restrict__ out) {
    int i = blockIdx.x * 256 + threadIdx.x;
    if (i < 1280) {
        int b = i / 10, o = i % 10;
        float s = bias[o];
#pragma unroll
        for (int f = 0; f < 10; ++f) {
            float feat = log1pf(ws[WS_ENERGY + b * 10 + f] + 1e-8f);
            s = fmaf(feat, W[o * 10 + f], s);
        }
        out[i] = s;
    }
}

extern "C" void kernel_launch(void* const* d_in, const int* in_sizes, int n_in,
                              void* d_out, int out_size, void* d_ws, size_t ws_size,
                              hipStream_t stream) {
    const float* images = (const float*)d_in[0];
    const float* conn_r = (const float*)d_in[1];
    const float* conn_i = (const float*)d_in[2];
    const float* phase  = (const float*)d_in[3];
    const float* gain   = (const float*)d_in[4];
    const float* W      = (const float*)d_in[5];
    const float* bias   = (const float*)d_in[6];
    float* ws  = (float*)d_ws;
    float* out = (float*)d_out;

    // zero WS_MAX + energy (floats 0..1343) — stream-ordered, capture-safe
    hipMemsetAsync(ws, 0, (WS_ENERGY + 1280) * sizeof(float), stream);
    hipLaunchKernelGGL(k_pre, dim3(189), dim3(256), 0, stream,
                       images, conn_r, conn_i, phase, gain, ws);
    hipLaunchKernelGGL(k_main, dim3(1024), dim3(256), 0, stream,
                       images, ws, ws + WS_ENERGY);
    hipLaunchKernelGGL(k_readout, dim3(5), dim3(256), 0, stream, ws, W, bias, out);
}

// Round 6
// 267.964 us; speedup vs baseline: 1.1880x; 1.1880x over previous
//
#include <hip/hip_runtime.h>
#include <cmath>

// PhaseAwareClassifier on MI355X — R23: col-owner waves at 2/SIMD + load
// bursts.
// R22 post-mortem: barrier-free col-owner worked (bit-exact, no scratch) but
// 1 wave/SIMD exposed ~75% of the step as ds_read/MFMA latency (20k cyc/step
// vs ~5k work). The 5.6M bank-conflict counter is the inherent 8-cyc b128
// minimum, not a lever. R23 keeps the structure, restores hiding:
//  - 512 thr / 8 waves, each owns 16 cols (one l-value): acc = 9x2 f32x4
//    = 72 VGPR -> fits the 256 cap implied by 2 waves/SIMD.
//  - __launch_bounds__(512) only (no min-waves hint; R19 lesson).
//  - kt body: ALL 20 ds_reads issued as one burst (static ar[9]/ai[9],
//    full unroll) before the MFMA block -> lgkm queue streams.
//  - still ZERO barriers in the t-loop; per-acc MFMA chain order unchanged
//    (one CPAIR per kt, kt ascending) -> bit-exact (absmax 0.0078125).
//  - t=1 kt<2 and t=9 tiles-7,8 truncations kept.
// LDS: conn 82,944 + OBP 73,728 + gsp 576 = 157,248 B -> 1 block/CU.

#define NSTEPS  10
#define INJ_ST  4
#define MT      144          // padded M (9 tiles of 16)

typedef __bf16 bf16x8 __attribute__((ext_vector_type(8)));
typedef __bf16 bf16x4 __attribute__((ext_vector_type(4)));
typedef short  short8 __attribute__((ext_vector_type(8)));
typedef float  f32x4  __attribute__((ext_vector_type(4)));

// workspace layout (float offsets)
#define WS_MAX    0          // 1      enc_max (uint-ordered float)
#define WS_ENERGY 64         // 1280   energy[b][10]
#define WS_GSP    2048       // 144    g2q[j] = -0.5*log2(e)*softplus(gain)
#define WS_CONN   4096       // 2 bf16 mats [20][144][8] chunked: Cr, Ci

// fused prep: blocks 0..97 = image absmax; blocks 98.. = conn + gsp tables
__global__ void k_pre(const float* __restrict__ img,
                      const float* __restrict__ cr, const float* __restrict__ ci,
                      const float* __restrict__ phase, const float* __restrict__ gain,
                      float* ws) {
    if (blockIdx.x < 98) {
        __shared__ float sm[256];
        float v = 0.f;
        for (int i = blockIdx.x * 256 + threadIdx.x; i < 128 * 28 * 28; i += 98 * 256)
            v = fmaxf(v, fabsf(img[i]));
        sm[threadIdx.x] = v;
        __syncthreads();
        for (int s = 128; s > 0; s >>= 1) {
            if (threadIdx.x < s) sm[threadIdx.x] = fmaxf(sm[threadIdx.x], sm[threadIdx.x + s]);
            __syncthreads();
        }
        if (threadIdx.x == 0)
            atomicMax((unsigned int*)(ws + WS_MAX), __float_as_uint(sm[0]));
        return;
    }
    int i = (blockIdx.x - 98) * 256 + threadIdx.x;
    __bf16* Cb = (__bf16*)(ws + WS_CONN);
    const int NCE = MT * 160;              // 23040 (m,k) pairs
    if (i < NCE) {
        int m = i / 160, k = i % 160;
        float vr = 0.f, vi = 0.f;
        if (m < 131 && k < 131) {
            float a = cr[k * 131 + m], b = ci[k * 131 + m];
            float ph = phase[m];
            float cp = cosf(ph), sp = sinf(ph);
            vr = a * cp - b * sp;
            vi = a * sp + b * cp;
        }
        int ca = ((k >> 3) * MT + m) * 8 + (k & 7);    // chunked addr
        Cb[ca]       = (__bf16)vr;
        Cb[NCE + ca] = (__bf16)vi;
    } else if (i < NCE + MT) {
        int j = i - NCE;
        float g = 0.f;
        if (j < 131) {
            float x = gain[j];
            g = (x > 20.f) ? x : log1pf(expf(x));  // softplus
        }
        ws[WS_GSP + j] = g * -0.72134754543f;       // -2*log2(e)*g / 4
    }
}

static __device__ __forceinline__ f32x4 MF(bf16x8 a, bf16x8 b, f32x4 c) {
    return __builtin_amdgcn_mfma_f32_16x16x32_bf16(a, b, c, 0, 0, 0);
}
static __device__ __forceinline__ bf16x8 bneg(bf16x8 a) {
    short8 t = __builtin_bit_cast(short8, a) ^ (short8)(short)0x8000;
    return __builtin_bit_cast(bf16x8, t);
}

// one complex 16x16 tile accumulation; order identical to R17..R22.
#define CPAIR(AR, AI, BR, BI, BNI, P)                                  \
    accr[P] = MF(AR, BR,  accr[P]);                                    \
    accr[P] = MF(AI, BNI, accr[P]);                                    \
    acci[P] = MF(AR, BI,  acci[P]);                                    \
    acci[P] = MF(AI, BR,  acci[P]);

__global__ __launch_bounds__(512)
void k_main(const float* __restrict__ img, const float* __restrict__ ws,
            float* __restrict__ energy) {
    __shared__ __bf16 CrL[18 * MT * 8];            // 41,472 B
    __shared__ __bf16 CiL[18 * MT * 8];            // 41,472 B
    __shared__ __bf16 OBP[2][8][18 * 16 * 8];      // 73,728 B  [r/i][wave][...]
    __shared__ float  gspL[144];                   // 576 B
    // total 157,248 B -> 1 block/CU, 8 waves = 2/SIMD, col-owner layout.

    const int tid  = threadIdx.x;
    const int lane = tid & 63;
    const int ln15 = lane & 15;
    const int quad = lane >> 4;
    const int w    = __builtin_amdgcn_readfirstlane(tid >> 6);  // 0..7
    const int b    = blockIdx.x >> 3;               // 8 blocks per image

    __bf16* __restrict__ OWr = &OBP[0][w][0];
    __bf16* __restrict__ OWi = &OBP[1][w][0];
    float* scrE = (float*)CrL;                      // alias: end only

    // injection scaling (identical rounding chain to R20..R22)
    const float mx = ws[WS_MAX];
    const float sc = (mx > 1e-8f) ? (1.02f / mx) : 1.02f;   // 0.85*4*0.3
    const int   imgb = b * 784 + (ln15 >> 2) * 28 + (ln15 & 3);

    // wave w owns cols [16w, 16w+16): single l-value, m = ln15
    const int   l   = ((blockIdx.x & 7) * 8 + w) & 63;
    const float wl  = 1.0f - fabsf((float)l - 32.0f) * (1.0f / 64.0f);

    // stage conn chunks 0..17 + gsp -> LDS (only barrier before the end)
    {
        const int4* srcR = (const int4*)(ws + WS_CONN);
        const int4* srcI = (const int4*)(ws + WS_CONN + (MT * 160 / 2));
        int4* dstR = (int4*)CrL;
        int4* dstI = (int4*)CiL;
        for (int i = tid; i < 2592; i += 512) { dstR[i] = srcR[i]; dstI[i] = srcI[i]; }
        if (tid < 144) gspL[tid] = ws[WS_GSP + tid];
    }

    f32x4 accr[9], acci[9];                         // p = mt
#pragma unroll
    for (int p = 0; p < 9; ++p) { accr[p] = (f32x4)0.f; acci[p] = (f32x4)0.f; }

    // injection: rows j<49 (tiles 0..3); one img load per row
    auto inj_add = [&]() {
#pragma unroll
        for (int mt = 0; mt < 4; ++mt) {
#pragma unroll
            for (int r = 0; r < 4; ++r) {
                int j = mt * 16 + quad * 4 + r;
                if (j < 49) {
                    int pi = j / 7, pj = j % 7;
                    float px = img[imgb + pi * 112 + pj * 4];
                    float t  = px * sc;
                    accr[mt][r] = fmaf(t, wl, accr[mt][r]);
                }
            }
        }
    };

    // epilogue: out = a * tanh(g*|f|)/|f| (0.25 folded in g2q), write own OB
    auto epilogue = [&]() {
#pragma unroll
        for (int mt = 0; mt < 9; ++mt) {
            f32x4 g2v = *(const f32x4*)(gspL + mt * 16 + quad * 4);
            bf16x4 pr, pi;
#pragma unroll
            for (int r = 0; r < 4; ++r) {
                float ar = accr[mt][r], ai = acci[mt][r];
                float mag2 = fmaf(ar, ar, fmaf(ai, ai, 1.6e-7f));
                float rsq  = __builtin_amdgcn_rsqf(mag2);
                float e    = __builtin_amdgcn_exp2f(g2v[r] * (mag2 * rsq));
                float u    = __builtin_amdgcn_rcpf(1.0f + e);
                float th   = fmaf(-2.0f, e * u, 1.0f);
                float scv  = th * rsq;
                pr[r] = (__bf16)(ar * scv); pi[r] = (__bf16)(ai * scv);
            }
            const int off = ((mt * 2 + (quad >> 1)) * 16 + ln15) * 8
                          + (quad & 1) * 4;
            *(bf16x4*)(OWr + off) = pr;
            *(bf16x4*)(OWi + off) = pi;
        }
    };

    __syncthreads();                                // conn + gsp staged

    inj_add();                                      // t = 0 (out is zero)
    epilogue();                                     // no barrier: wave-private

    // ---- time loop: ZERO barriers (each wave owns its columns) ----
#pragma unroll 1
    for (int t = 1; t < NSTEPS - 1; ++t) {
#pragma unroll
        for (int p = 0; p < 9; ++p) { accr[p] *= 0.85f; acci[p] *= 0.85f; }
        if (t < INJ_ST) inj_add();

        // t=1: out(0) rows >=49 exactly zero -> kt 0,1 only.
        const int ktEnd = (t == 1) ? 2 : 5;
        // kch 18,19 remap to chunk 17 (zeros both sides). unroll(1): R15.
#pragma unroll 1
        for (int kt = 0; kt < ktEnd; ++kt) {
            const int kch = kt * 4 + quad;
            const int rk  = (kch > 17) ? 17 : kch;
            // ---- load burst: 2 B + 18 A reads, then MFMA block ----
            const int bb  = (rk * 16 + ln15) * 8;
            bf16x8 br = *(const bf16x8*)(OWr + bb);
            bf16x8 bi = *(const bf16x8*)(OWi + bb);
            const int ab = (rk * MT + ln15) * 8;
            bf16x8 ar[9], ai[9];
#pragma unroll
            for (int mt = 0; mt < 9; ++mt) {
                ar[mt] = *(const bf16x8*)(CrL + ab + mt * 128);
                ai[mt] = *(const bf16x8*)(CiL + ab + mt * 128);
            }
            bf16x8 bn = bneg(bi);
#pragma unroll
            for (int mt = 0; mt < 9; ++mt) {
                CPAIR(ar[mt], ai[mt], br, bi, bn, mt)
            }
        }
        epilogue();                                 // wave-private, no barrier
    }

    // ---- t = 9: only rows 121..130 (tiles 7,8) feed energy; all waves ----
    {
        accr[7] *= 0.85f; acci[7] *= 0.85f;
        accr[8] *= 0.85f; acci[8] *= 0.85f;
#pragma unroll 1
        for (int kt = 0; kt < 5; ++kt) {
            const int kch = kt * 4 + quad;
            const int rk  = (kch > 17) ? 17 : kch;
            const int bb  = (rk * 16 + ln15) * 8;
            bf16x8 br = *(const bf16x8*)(OWr + bb);
            bf16x8 bi = *(const bf16x8*)(OWi + bb);
            const int ab = (rk * MT + ln15) * 8;
            bf16x8 ar7 = *(const bf16x8*)(CrL + ab + 7 * 128);
            bf16x8 ai7 = *(const bf16x8*)(CiL + ab + 7 * 128);
            bf16x8 ar8 = *(const bf16x8*)(CrL + ab + 8 * 128);
            bf16x8 ai8 = *(const bf16x8*)(CiL + ab + 8 * 128);
            bf16x8 bn = bneg(bi);
            CPAIR(ar7, ai7, br, bi, bn, 7)
            CPAIR(ar8, ai8, br, bi, bn, 8)
        }
    }
    __syncthreads();       // all CrL A-reads done before scrE (alias) writes

    // energy rows: fp32 |out|^2 -> scrE (aliases CrL)
#pragma unroll
    for (int mt = 7; mt < 9; ++mt) {
        const int n = w * 16 + ln15;
#pragma unroll
        for (int r = 0; r < 4; ++r) {
            int j = mt * 16 + quad * 4 + r;
            if (j >= 121 && j <= 130) {
                float ar = accr[mt][r], ai = acci[mt][r];
                float mag2 = fmaf(ar, ar, fmaf(ai, ai, 1.6e-7f));
                float rsq  = __builtin_amdgcn_rsqf(mag2);
                float e    = __builtin_amdgcn_exp2f(gspL[j] * (mag2 * rsq));
                float u    = __builtin_amdgcn_rcpf(1.0f + e);
                float th   = fmaf(-2.0f, e * u, 1.0f);
                float scv  = th * rsq;
                float orv = ar * scv, oiv = ai * scv;
                scrE[(j - 121) * 128 + n] = orv * orv + oiv * oiv;
            }
        }
    }
    __syncthreads();       // scrE complete

    // ---- energy: scrE[10][128] holds exact fp32 |out|^2 ----
    if (tid < 10) {
        float ssum = 0.f;
        for (int cc = 0; cc < 128; ++cc) ssum += scrE[tid * 128 + cc];
        atomicAdd(energy + b * 10 + tid, ssum);
    }
}

__global__ void k_readout(const float* __restrict__ ws,
                          const float* __restrict__ W,
                          const float* __restrict__ bias,
                          float* __restrict__ out) {
    int i = blockIdx.x * 256 + threadIdx.x;
    if (i < 1280) {
        int b = i / 10, o = i % 10;
        float s = bias[o];
#pragma unroll
        for (int f = 0; f < 10; ++f) {
            float feat = log1pf(ws[WS_ENERGY + b * 10 + f] + 1e-8f);
            s = fmaf(feat, W[o * 10 + f], s);
        }
        out[i] = s;
    }
}

extern "C" void kernel_launch(void* const* d_in, const int* in_sizes, int n_in,
                              void* d_out, int out_size, void* d_ws, size_t ws_size,
                              hipStream_t stream) {
    const float* images = (const float*)d_in[0];
    const float* conn_r = (const float*)d_in[1];
    const float* conn_i = (const float*)d_in[2];
    const float* phase  = (const float*)d_in[3];
    const float* gain   = (const float*)d_in[4];
    const float* W      = (const float*)d_in[5];
    const float* bias   = (const float*)d_in[6];
    float* ws  = (float*)d_ws;
    float* out = (float*)d_out;

    // zero WS_MAX + energy (floats 0..1343) — stream-ordered, capture-safe
    hipMemsetAsync(ws, 0, (WS_ENERGY + 1280) * sizeof(float), stream);
    hipLaunchKernelGGL(k_pre, dim3(189), dim3(256), 0, stream,
                       images, conn_r, conn_i, phase, gain, ws);
    hipLaunchKernelGGL(k_main, dim3(1024), dim3(512), 0, stream,
                       images, ws, ws + WS_ENERGY);
    hipLaunchKernelGGL(k_readout, dim3(5), dim3(256), 0, stream, ws, W, bias, out);
}